// Round 1
// baseline (427.652 us; speedup 1.0000x reference)
//
#include <hip/hip_runtime.h>
#include <math.h>

// Problem constants (from reference)
#define RCUT   6.0f
#define RMINF  0.5f
#define LSPAN  5.5f          // RC - RMIN
constexpr int BETA = 12, M1 = 24, M2 = 6;
constexpr int B_ = 4, N_ = 1024, NT_ = 2, MN_ = 128;
constexpr int K_ = NT_ * MN_;        // 256
constexpr int NFEAT = M1 * M2;       // 144
constexpr int HID = 128;
constexpr float PI_F = 3.14159265358979323846f;

// Output layout: Etot(4) | Ei(4096) | Force(4*1024*3) | Virial(36)
constexpr int EI_OFF = B_;                  // 4
constexpr int F_OFF  = B_ + B_ * N_;        // 4100
constexpr int V_OFF  = F_OFF + B_ * N_ * 3; // 16388

__global__ void zero_out_kernel(float* __restrict__ out, int ntot) {
    int i = blockIdx.x * blockDim.x + threadIdx.x;
    if (i < ntot) out[i] = 0.0f;
}

__global__ __launch_bounds__(256) void cheby_main(
    const int*   __restrict__ list_neigh,   // (B,N,K)
    const int*   __restrict__ type_map,     // (N,)
    const float* __restrict__ imagedr,      // (B,N,K,4)
    const float* __restrict__ c_param,      // (NT,NT,M1,BETA)
    const float* __restrict__ scale,        // (NFEAT,)
    const float* __restrict__ W0,           // (NT,NFEAT,HID)
    const float* __restrict__ b0,           // (NT,HID)
    const float* __restrict__ W1,           // (NT,HID,HID)
    const float* __restrict__ b1,           // (NT,HID)
    const float* __restrict__ W2,           // (NT,HID)
    const float* __restrict__ b2,           // (NT,)
    const float* __restrict__ eshift,       // (NT,)
    float* __restrict__ out)
{
    __shared__ float c_sh[NT_ * M1 * BETA];     // 576
    __shared__ float s_sh[K_ * 25];             // padded 24->25
    __shared__ float sr_sh[K_ * 5];             // padded 4->5
    __shared__ float Rpart[2 * 96];
    __shared__ float R_sh[M1 * 4];
    __shared__ float dR_sh[M1 * 4];
    __shared__ float feat_sh[NFEAT];
    __shared__ float dfeat_sh[NFEAT];
    __shared__ float h_sh[HID];
    __shared__ float t1_sh[HID];
    __shared__ float dz1_sh[HID];
    __shared__ float dz0_sh[HID];
    __shared__ float red12[12 * 4];
    __shared__ float red1[4];

    const int tid  = threadIdx.x;
    const int lane = tid & 63;
    const int wid  = tid >> 6;
    const int bn = blockIdx.x;
    const int b  = bn / N_;
    const int n  = bn % N_;
    const int tn = type_map[n];

    // ---- load c_param slice for this atom type: [tk][f][j] ----
    for (int i = tid; i < NT_ * M1 * BETA; i += 256)
        c_sh[i] = c_param[tn * (NT_ * M1 * BETA) + i];

    // ---- per-neighbor forward (thread k = tid) ----
    const int k  = tid;
    const int tk = k >> 7;                 // k / MN
    const int lni = list_neigh[(size_t)bn * K_ + k];
    const float valid = (lni >= 0) ? 1.0f : 0.0f;

    const float4 dr4 = reinterpret_cast<const float4*>(imagedr)[(size_t)bn * K_ + k];
    const float rx = dr4.y, ry = dr4.z, rz = dr4.w;
    const float r  = sqrtf(rx*rx + ry*ry + rz*rz + 1e-12f);
    const float uraw = (r - RMINF) / LSPAN;
    const float u  = fminf(fmaxf(uraw, 0.0f), 1.0f);
    const float fc = 0.5f * (cosf(PI_F * u) + 1.0f) * valid;
    const float x  = 2.0f * (r - RMINF) / LSPAN - 1.0f;

    float T[BETA];
    T[0] = 1.0f; T[1] = x;
#pragma unroll
    for (int j = 2; j < BETA; ++j) T[j] = 2.0f * x * T[j-1] - T[j-2];

    const float inv_r = 1.0f / r;
    const float sr0 = valid;
    const float sr1 = valid * rx * inv_r;
    const float sr2 = valid * ry * inv_r;
    const float sr3 = valid * rz * inv_r;

    __syncthreads();   // c_sh ready

    float sig[M1];
    const float* crow = &c_sh[tk * M1 * BETA];
#pragma unroll
    for (int f = 0; f < M1; ++f) {
        float acc = 0.0f;
#pragma unroll
        for (int j = 0; j < BETA; ++j) acc += T[j] * crow[f * BETA + j];
        sig[f] = acc;
        s_sh[k * 25 + f] = fc * acc;
    }
    sr_sh[k * 5 + 0] = sr0;
    sr_sh[k * 5 + 1] = sr1;
    sr_sh[k * 5 + 2] = sr2;
    sr_sh[k * 5 + 3] = sr3;
    __syncthreads();

    // ---- R[f][c] = (1/MN) * sum_k s[k][f] * sr[k][c]  (split-k over 192 threads) ----
    if (tid < 192) {
        const int half = tid / 96, tt = tid % 96;
        const int f = tt >> 2, c = tt & 3;
        const int k0 = half * 128;
        float acc = 0.0f;
        for (int kk = k0; kk < k0 + 128; ++kk)
            acc += s_sh[kk * 25 + f] * sr_sh[kk * 5 + c];
        Rpart[half * 96 + tt] = acc;
    }
    __syncthreads();
    if (tid < 96) R_sh[tid] = (Rpart[tid] + Rpart[96 + tid]) * (1.0f / MN_);
    __syncthreads();

    // ---- feat[f][g] = sum_c R[f][c]*R[g][c], scaled ----
    if (tid < NFEAT) {
        const int f = tid / 6, g = tid % 6;
        float acc = 0.0f;
#pragma unroll
        for (int c = 0; c < 4; ++c) acc += R_sh[f * 4 + c] * R_sh[g * 4 + c];
        feat_sh[tid] = acc * scale[tid];
    }
    __syncthreads();

    // ---- MLP forward: layer 0 ----
    if (tid < HID) {
        float acc = b0[tn * HID + tid];
        const float* w0c = W0 + (size_t)tn * NFEAT * HID + tid;
        for (int f = 0; f < NFEAT; ++f) acc += feat_sh[f] * w0c[f * HID];
        h_sh[tid] = tanhf(acc);
    }
    __syncthreads();

    // ---- layer 1 + skip + E terms ----
    float Eterm = 0.0f;
    if (tid < HID) {
        float acc = b1[tn * HID + tid];
        const float* w1c = W1 + (size_t)tn * HID * HID + tid;
        for (int h = 0; h < HID; ++h) acc += h_sh[h] * w1c[h * HID];
        const float t1 = tanhf(acc);
        t1_sh[tid] = t1;
        Eterm = (t1 + h_sh[tid]) * W2[tn * HID + tid];
    }
    // block-reduce E
    {
        float v = Eterm;
#pragma unroll
        for (int m = 32; m >= 1; m >>= 1) v += __shfl_xor(v, m);
        if (lane == 0) red1[wid] = v;
    }
    __syncthreads();
    if (tid == 0) {
        const float E = red1[0] + red1[1] + red1[2] + red1[3] + b2[tn] + eshift[tn];
        out[EI_OFF + bn] = E;
        atomicAdd(&out[b], E);
    }

    // ---- MLP backward ----
    if (tid < HID) {
        const float t1 = t1_sh[tid];
        dz1_sh[tid] = W2[tn * HID + tid] * (1.0f - t1 * t1);
    }
    __syncthreads();
    if (tid < HID) {
        const float4* w1row = reinterpret_cast<const float4*>(W1 + (size_t)(tn * HID + tid) * HID);
        float acc = W2[tn * HID + tid];   // skip-connection term
        for (int g4 = 0; g4 < HID / 4; ++g4) {
            const float4 w = w1row[g4];
            acc += w.x * dz1_sh[g4*4+0] + w.y * dz1_sh[g4*4+1]
                 + w.z * dz1_sh[g4*4+2] + w.w * dz1_sh[g4*4+3];
        }
        const float hh = h_sh[tid];
        dz0_sh[tid] = acc * (1.0f - hh * hh);
    }
    __syncthreads();
    if (tid < NFEAT) {
        const float4* w0row = reinterpret_cast<const float4*>(W0 + (size_t)(tn * NFEAT + tid) * HID);
        float acc = 0.0f;
        for (int h4 = 0; h4 < HID / 4; ++h4) {
            const float4 w = w0row[h4];
            acc += w.x * dz0_sh[h4*4+0] + w.y * dz0_sh[h4*4+1]
                 + w.z * dz0_sh[h4*4+2] + w.w * dz0_sh[h4*4+3];
        }
        dfeat_sh[tid] = acc * scale[tid];   // grad wrt unscaled feat
    }
    __syncthreads();

    // ---- dR[p][c] = sum_{g<6} dfeat[p,g]*R[g,c] + (p<6) sum_f dfeat[f,p]*R[f,c], /MN ----
    if (tid < 96) {
        const int p = tid >> 2, c = tid & 3;
        float acc = 0.0f;
#pragma unroll
        for (int g = 0; g < M2; ++g) acc += dfeat_sh[p * 6 + g] * R_sh[g * 4 + c];
        if (p < M2) {
            for (int f = 0; f < M1; ++f) acc += dfeat_sh[f * 6 + p] * R_sh[f * 4 + c];
        }
        dR_sh[p * 4 + c] = acc * (1.0f / MN_);
    }
    __syncthreads();

    // ---- per-neighbor backward ----
    float cj[BETA];
#pragma unroll
    for (int j = 0; j < BETA; ++j) cj[j] = 0.0f;
    float dsr1 = 0.0f, dsr2 = 0.0f, dsr3 = 0.0f, dfc = 0.0f;
#pragma unroll
    for (int f = 0; f < M1; ++f) {
        const float d0 = dR_sh[f*4+0], d1 = dR_sh[f*4+1], d2 = dR_sh[f*4+2], d3 = dR_sh[f*4+3];
        const float dsf = d0 * sr0 + d1 * sr1 + d2 * sr2 + d3 * sr3;
        const float sf = sig[f];
        dfc += dsf * sf;
        const float dsg = dsf * fc;
#pragma unroll
        for (int j = 0; j < BETA; ++j) cj[j] += dsg * crow[f * BETA + j];
        const float sk = fc * sf;
        dsr1 += d1 * sk; dsr2 += d2 * sk; dsr3 += d3 * sk;
    }
    // dE/dx = sum_j cj[j] * T'_j ; T'_0=0, T'_1=1, T'_n = 2T_{n-1} + 2x T'_{n-1} - T'_{n-2}
    float dx = cj[1];
    float tpm1 = 1.0f, tpm2 = 0.0f;
#pragma unroll
    for (int j = 2; j < BETA; ++j) {
        const float tp = 2.0f * T[j-1] + 2.0f * x * tpm1 - tpm2;
        dx += cj[j] * tp;
        tpm2 = tpm1; tpm1 = tp;
    }
    float dfcdr = 0.0f;
    if (uraw > 0.0f && uraw < 1.0f)
        dfcdr = -0.5f * PI_F * sinf(PI_F * u) * valid / LSPAN;
    const float drt = dx * (2.0f / LSPAN) + dfc * dfcdr;
    const float Sdot = dsr1 * rx + dsr2 * ry + dsr3 * rz;
    const float common = drt * inv_r - valid * Sdot * inv_r * inv_r * inv_r;
    const float gx = common * rx + valid * dsr1 * inv_r;
    const float gy = common * ry + valid * dsr2 * inv_r;
    const float gz = common * rz + valid * dsr3 * inv_r;

    // neighbor scatter: Force[b, lni] -= g
    if (lni >= 0) {
        float* fp = out + F_OFF + ((size_t)b * N_ + lni) * 3;
        atomicAdd(fp + 0, -gx);
        atomicAdd(fp + 1, -gy);
        atomicAdd(fp + 2, -gz);
    }

    // block reduce: self force (3) + virial (9)
    float vals[12];
    vals[0] = gx; vals[1] = gy; vals[2] = gz;
    vals[3] = -rx * gx; vals[4]  = -rx * gy; vals[5]  = -rx * gz;
    vals[6] = -ry * gx; vals[7]  = -ry * gy; vals[8]  = -ry * gz;
    vals[9] = -rz * gx; vals[10] = -rz * gy; vals[11] = -rz * gz;
#pragma unroll
    for (int i = 0; i < 12; ++i) {
        float v = vals[i];
#pragma unroll
        for (int m = 32; m >= 1; m >>= 1) v += __shfl_xor(v, m);
        if (lane == 0) red12[i * 4 + wid] = v;
    }
    __syncthreads();
    if (tid < 12) {
        const float v = red12[tid*4+0] + red12[tid*4+1] + red12[tid*4+2] + red12[tid*4+3];
        if (tid < 3) atomicAdd(&out[F_OFF + ((size_t)b * N_ + n) * 3 + tid], v);
        else         atomicAdd(&out[V_OFF + b * 9 + (tid - 3)], v);
    }
}

extern "C" void kernel_launch(void* const* d_in, const int* in_sizes, int n_in,
                              void* d_out, int out_size, void* d_ws, size_t ws_size,
                              hipStream_t stream) {
    float* out = (float*)d_out;
    zero_out_kernel<<<(out_size + 255) / 256, 256, 0, stream>>>(out, out_size);
    cheby_main<<<B_ * N_, 256, 0, stream>>>(
        (const int*)d_in[0],     // list_neigh
        (const int*)d_in[1],     // Imagetype_map
        (const float*)d_in[3],   // ImageDR
        (const float*)d_in[6],   // c_param
        (const float*)d_in[7],   // scale
        (const float*)d_in[8],   // W0
        (const float*)d_in[9],   // b0
        (const float*)d_in[10],  // W1
        (const float*)d_in[11],  // b1
        (const float*)d_in[12],  // W2
        (const float*)d_in[13],  // b2
        (const float*)d_in[14],  // ener_shift
        out);
}